// Round 1
// baseline (274.408 us; speedup 1.0000x reference)
//
#include <hip/hip_runtime.h>

typedef __bf16 bf16;
typedef __bf16 bf16x4 __attribute__((ext_vector_type(4)));
typedef __bf16 bf16x8 __attribute__((ext_vector_type(8)));
typedef float  f32x4  __attribute__((ext_vector_type(4)));

#define CIN   256
#define COUT  256
#define KK    9
#define KDIM  (CIN * KK)     // 2304
#define KCHUNK 1152          // K split in 2 chunks -> LDS 37 KB
#define SSTRIDE 1160         // KCHUNK + 8 bf16 pad (16B aligned, 2-way banks)

// ---------------------------------------------------------------------------
// Kernel 1: weight [O][C][3][3] fp32  ->  bf16 [O][tap*256 + c]
// ---------------------------------------------------------------------------
__global__ void pack_weight_k(const float* __restrict__ w, bf16* __restrict__ wq) {
    int i = blockIdx.x * 256 + threadIdx.x;        // < 589824
    int o = i / KDIM;
    int r = i - o * KDIM;
    int c = r / KK;
    int tap = r - c * KK;
    wq[o * KDIM + tap * CIN + c] = (bf16)w[i];
}

// ---------------------------------------------------------------------------
// Kernel 2: x [B][C][64][64] fp32 -> channels-last bf16 xt [B][64][64][C]
// LDS-tiled 64ch x 64px transpose
// ---------------------------------------------------------------------------
__global__ void transpose_x_k(const float* __restrict__ x, bf16* __restrict__ xt) {
    __shared__ bf16 tile[64][72];
    int wg = blockIdx.x;          // 1024 = 4 b * 4 ctile * 64 ptile
    int pt = wg & 63;
    int ct = (wg >> 6) & 3;
    int b  = wg >> 8;
    int lane = threadIdx.x & 63;
    int row  = threadIdx.x >> 6;  // 0..3
    const float* src = x + ((size_t)(b * 256 + ct * 64)) * 4096 + pt * 64;
    for (int c = row; c < 64; c += 4)
        tile[c][lane] = (bf16)src[(size_t)c * 4096 + lane];
    __syncthreads();
    bf16* dst = xt + ((size_t)(b * 4096 + pt * 64)) * 256 + ct * 64;
    for (int p = row; p < 64; p += 4)
        dst[(size_t)p * 256 + lane] = tile[lane][p];
}

// ---------------------------------------------------------------------------
// Kernel 3: fused bilinear sampling -> LDS -> MFMA GEMM
// WG = 256 threads (4 waves), one 16-pixel tile; M=256 split 4 waves x 4 mtiles
// ---------------------------------------------------------------------------
__global__ __launch_bounds__(256) void deform_gemm_k(
    const bf16*  __restrict__ xt,
    const float* __restrict__ off,
    const bf16*  __restrict__ wq,
    const float* __restrict__ bias,
    float*       __restrict__ out) {

    __shared__ bf16 S[16][SSTRIDE];   // 37,120 B

    int tid  = threadIdx.x;
    int wave = tid >> 6;
    int lane = tid & 63;
    int quad = lane >> 4;
    int l16  = lane & 15;
    int pix0 = blockIdx.x * 16;       // global pixel base

    f32x4 acc[4];
    #pragma unroll
    for (int t = 0; t < 4; ++t) acc[t] = (f32x4){0.f, 0.f, 0.f, 0.f};

    for (int chunk = 0; chunk < 2; ++chunk) {
        int klo = chunk * KCHUNK;

        // ---------------- sampling phase: fill S[n][k-klo] ----------------
        #pragma unroll
        for (int i = 0; i < 4; ++i) {
            int n    = wave * 4 + i;
            int pg   = pix0 + n;
            int b    = pg >> 12;
            int pimg = pg & 4095;
            int y  = pimg >> 6;
            int xx = pimg & 63;
            const float* ob = off + (size_t)b * 18 * 4096 + pimg;
            int c = lane * 4;                       // 4 channels per lane
            const bf16* xb = xt + (size_t)b * 4096 * 256 + c;

            for (int tap = 0; tap < 9; ++tap) {
                int kg = tap * CIN + c;             // global k of this lane
                if (kg < klo || kg >= klo + KCHUNK) continue;

                float oy = ob[(size_t)(2 * tap) * 4096];
                float ox = ob[(size_t)(2 * tap + 1) * 4096];
                float py = (float)(y - 1 + tap / 3) + oy;
                float px = (float)(xx - 1 + tap % 3) + ox;
                float fy = floorf(py), fx = floorf(px);
                int   y0 = (int)fy,    x0 = (int)fx;
                float wy1 = py - fy, wx1 = px - fx;
                float wy0 = 1.f - wy1, wx0 = 1.f - wx1;

                float a0 = 0.f, a1 = 0.f, a2 = 0.f, a3 = 0.f;
                #define CORNER(YC, XC, WT)                                             \
                    if ((unsigned)(YC) < 64u && (unsigned)(XC) < 64u) {                \
                        bf16x4 v = *reinterpret_cast<const bf16x4*>(                   \
                            xb + ((size_t)(YC) * 64 + (XC)) * 256);                    \
                        float wt = (WT);                                               \
                        a0 += wt * (float)v[0]; a1 += wt * (float)v[1];                \
                        a2 += wt * (float)v[2]; a3 += wt * (float)v[3];                \
                    }
                CORNER(y0,     x0,     wy0 * wx0)
                CORNER(y0,     x0 + 1, wy0 * wx1)
                CORNER(y0 + 1, x0,     wy1 * wx0)
                CORNER(y0 + 1, x0 + 1, wy1 * wx1)
                #undef CORNER

                bf16x4 sv;
                sv[0] = (bf16)a0; sv[1] = (bf16)a1;
                sv[2] = (bf16)a2; sv[3] = (bf16)a3;
                *reinterpret_cast<bf16x4*>(&S[n][kg - klo]) = sv;
            }
        }
        __syncthreads();

        // ---------------- GEMM phase over this K chunk ----------------
        const bf16* wp = wq + (size_t)(wave * 64 + l16) * KDIM + klo + quad * 8;
        const bf16* sp = &S[l16][quad * 8];
        for (int kk = 0; kk < KCHUNK; kk += 32) {
            bf16x8 bfrag = *reinterpret_cast<const bf16x8*>(sp + kk);
            bf16x8 a0 = *reinterpret_cast<const bf16x8*>(wp + kk);
            bf16x8 a1 = *reinterpret_cast<const bf16x8*>(wp + (size_t)16 * KDIM + kk);
            bf16x8 a2 = *reinterpret_cast<const bf16x8*>(wp + (size_t)32 * KDIM + kk);
            bf16x8 a3 = *reinterpret_cast<const bf16x8*>(wp + (size_t)48 * KDIM + kk);
            acc[0] = __builtin_amdgcn_mfma_f32_16x16x32_bf16(a0, bfrag, acc[0], 0, 0, 0);
            acc[1] = __builtin_amdgcn_mfma_f32_16x16x32_bf16(a1, bfrag, acc[1], 0, 0, 0);
            acc[2] = __builtin_amdgcn_mfma_f32_16x16x32_bf16(a2, bfrag, acc[2], 0, 0, 0);
            acc[3] = __builtin_amdgcn_mfma_f32_16x16x32_bf16(a3, bfrag, acc[3], 0, 0, 0);
        }
        __syncthreads();   // S reused next chunk
    }

    // ---------------- epilogue: C/D layout col=l16, row=quad*4+r ----------------
    int pg   = pix0 + l16;
    int b    = pg >> 12;
    int pimg = pg & 4095;
    #pragma unroll
    for (int t = 0; t < 4; ++t) {
        int m = wave * 64 + t * 16 + quad * 4;
        float* op = out + ((size_t)(b * 256 + m)) * 4096 + pimg;
        #pragma unroll
        for (int r = 0; r < 4; ++r)
            op[(size_t)r * 4096] = acc[t][r] + bias[m + r];
    }
}

// ---------------------------------------------------------------------------
extern "C" void kernel_launch(void* const* d_in, const int* in_sizes, int n_in,
                              void* d_out, int out_size, void* d_ws, size_t ws_size,
                              hipStream_t stream) {
    const float* x    = (const float*)d_in[0];   // [4,256,64,64]
    const float* off  = (const float*)d_in[1];   // [4,18,64,64]
    const float* w    = (const float*)d_in[2];   // [256,256,3,3]
    const float* bias = (const float*)d_in[3];   // [256]
    float* out = (float*)d_out;                  // [4,256,64,64]

    bf16* wq = (bf16*)d_ws;                              // 1,179,648 B
    bf16* xt = (bf16*)((char*)d_ws + (size_t)589824 * 2); // 8,388,608 B

    pack_weight_k<<<2304, 256, 0, stream>>>(w, wq);
    transpose_x_k<<<1024, 256, 0, stream>>>(x, xt);
    deform_gemm_k<<<1024, 256, 0, stream>>>(xt, off, wq, bias, out);
}

// Round 2
// 200.202 us; speedup vs baseline: 1.3707x; 1.3707x over previous
//
#include <hip/hip_runtime.h>

typedef __bf16 bf16;
typedef __bf16 bf16x4 __attribute__((ext_vector_type(4)));
typedef __bf16 bf16x8 __attribute__((ext_vector_type(8)));
typedef float  f32x4  __attribute__((ext_vector_type(4)));

#define CIN   256
#define COUT  256
#define KK    9
#define KDIM  (CIN * KK)     // 2304
#define KITERS 72            // KDIM / 32
#define PXW   32             // pixels per WG
#define SROW  264            // 256 + 8 bf16 pad (row = 528 B, 16B-aligned)

// ---------------------------------------------------------------------------
// Kernel 1: weight [O][C][3][3] fp32 -> MFMA-fragment-ordered bf16:
//   wq[ ((m*72 + kt)*64 + lane)*8 + j ]  holds  W[o = m*16+l16][k = kt*32+quad*8+j]
//   with lane = quad*16 + l16, k -> (tap = k>>8, c = k&255), W src = w[o][c][tap].
// A wave's A-frag load for (mtile m, k-iter kt) is 64 lanes x 16 B contiguous.
// ---------------------------------------------------------------------------
__global__ void pack_weight_k(const float* __restrict__ w, bf16* __restrict__ wq) {
    int idx  = blockIdx.x * 256 + threadIdx.x;   // < 589824
    int j    = idx & 7;
    int lane = (idx >> 3) & 63;
    int rest = idx >> 9;            // m*72 + kt
    int kt   = rest % KITERS;
    int m    = rest / KITERS;
    int l16  = lane & 15;
    int quad = lane >> 4;
    int o    = m * 16 + l16;
    int k    = kt * 32 + quad * 8 + j;
    int tap  = k >> 8;
    int c    = k & 255;
    wq[idx] = (bf16)w[(size_t)o * KDIM + c * KK + tap];
}

// ---------------------------------------------------------------------------
// Kernel 2: x [B][C][64][64] fp32 -> channels-last bf16 xt [B][64][64][C]
// ---------------------------------------------------------------------------
__global__ void transpose_x_k(const float* __restrict__ x, bf16* __restrict__ xt) {
    __shared__ bf16 tile[64][72];
    int wg = blockIdx.x;          // 1024 = 4 b * 4 ctile * 64 ptile
    int pt = wg & 63;
    int ct = (wg >> 6) & 3;
    int b  = wg >> 8;
    int lane = threadIdx.x & 63;
    int row  = threadIdx.x >> 6;  // 0..3
    const float* src = x + ((size_t)(b * 256 + ct * 64)) * 4096 + pt * 64;
    for (int c = row; c < 64; c += 4)
        tile[c][lane] = (bf16)src[(size_t)c * 4096 + lane];
    __syncthreads();
    bf16* dst = xt + ((size_t)(b * 4096 + pt * 64)) * 256 + ct * 64;
    for (int p = row; p < 64; p += 4)
        dst[(size_t)p * 256 + lane] = tile[lane][p];
}

// ---------------------------------------------------------------------------
// Kernel 3: fused sampling -> LDS -> MFMA GEMM
// WG = 256 thr (4 waves), 32 pixels. Chunk = one tap (k=256).
// Wave: M=64 (4 mtiles) x N=32 (2 ntiles), acc = 4x2 f32x4 = 32 VGPR.
// ---------------------------------------------------------------------------
__global__ __launch_bounds__(256) void deform_gemm_k(
    const bf16*  __restrict__ xt,
    const float* __restrict__ off,
    const bf16*  __restrict__ wq,
    const float* __restrict__ bias,
    float*       __restrict__ out) {

    __shared__ bf16 S[PXW][SROW];   // 16,896 B

    int tid  = threadIdx.x;
    int wave = tid >> 6;
    int lane = tid & 63;
    int quad = lane >> 4;
    int l16  = lane & 15;
    int pix0 = blockIdx.x * PXW;

    f32x4 acc[4][2];
    #pragma unroll
    for (int t = 0; t < 4; ++t)
        #pragma unroll
        for (int nt = 0; nt < 2; ++nt)
            acc[t][nt] = (f32x4){0.f, 0.f, 0.f, 0.f};

    int c = lane * 4;   // this lane's 4 channels

    for (int tap = 0; tap < KK; ++tap) {
        int ty = tap / 3 - 1;
        int tx = tap % 3 - 1;

        // -------- sampling: wave fills rows n = wave*8 .. wave*8+7 --------
        #pragma unroll
        for (int i = 0; i < 8; ++i) {
            int n    = wave * 8 + i;
            int pg   = pix0 + n;
            int b    = pg >> 12;
            int pimg = pg & 4095;
            int y  = pimg >> 6;
            int xx = pimg & 63;
            const float* ob = off + (size_t)b * 18 * 4096 + pimg;
            float oy = ob[(size_t)(2 * tap) * 4096];
            float ox = ob[(size_t)(2 * tap + 1) * 4096];
            float py = (float)(y + ty) + oy;
            float px = (float)(xx + tx) + ox;
            float fy = floorf(py), fx = floorf(px);
            int   y0 = (int)fy,    x0 = (int)fx;
            float wy1 = py - fy, wx1 = px - fx;
            float wy0 = 1.f - wy1, wx0 = 1.f - wx1;

            const bf16* xb = xt + (size_t)b * 4096 * 256 + c;
            float a0 = 0.f, a1 = 0.f, a2 = 0.f, a3 = 0.f;
            #define CORNER(YC, XC, WT)                                             \
                if ((unsigned)(YC) < 64u && (unsigned)(XC) < 64u) {                \
                    bf16x4 v = *reinterpret_cast<const bf16x4*>(                   \
                        xb + ((size_t)(YC) * 64 + (XC)) * 256);                    \
                    float wt = (WT);                                               \
                    a0 += wt * (float)v[0]; a1 += wt * (float)v[1];                \
                    a2 += wt * (float)v[2]; a3 += wt * (float)v[3];                \
                }
            CORNER(y0,     x0,     wy0 * wx0)
            CORNER(y0,     x0 + 1, wy0 * wx1)
            CORNER(y0 + 1, x0,     wy1 * wx0)
            CORNER(y0 + 1, x0 + 1, wy1 * wx1)
            #undef CORNER

            bf16x4 sv;
            sv[0] = (bf16)a0; sv[1] = (bf16)a1;
            sv[2] = (bf16)a2; sv[3] = (bf16)a3;
            *reinterpret_cast<bf16x4*>(&S[n][c]) = sv;
        }
        __syncthreads();

        // -------- GEMM over this tap's k=256 --------
        const bf16* sp0 = &S[l16][quad * 8];
        const bf16* sp1 = &S[16 + l16][quad * 8];
        const bf16* ap  = wq + ((size_t)((wave * 4) * KITERS + tap * 8) * 64 + lane) * 8;
        #pragma unroll
        for (int kki = 0; kki < 8; ++kki) {
            bf16x8 b0 = *reinterpret_cast<const bf16x8*>(sp0 + kki * 32);
            bf16x8 b1 = *reinterpret_cast<const bf16x8*>(sp1 + kki * 32);
            #pragma unroll
            for (int t = 0; t < 4; ++t) {
                bf16x8 a = *reinterpret_cast<const bf16x8*>(
                    ap + ((size_t)(t * KITERS + kki) * 64) * 8);
                acc[t][0] = __builtin_amdgcn_mfma_f32_16x16x32_bf16(a, b0, acc[t][0], 0, 0, 0);
                acc[t][1] = __builtin_amdgcn_mfma_f32_16x16x32_bf16(a, b1, acc[t][1], 0, 0, 0);
            }
        }
        __syncthreads();   // S reused next tap
    }

    // -------- epilogue: C/D layout col=l16, row=quad*4+r --------
    #pragma unroll
    for (int nt = 0; nt < 2; ++nt) {
        int pg   = pix0 + nt * 16 + l16;
        int b    = pg >> 12;
        int pimg = pg & 4095;
        #pragma unroll
        for (int t = 0; t < 4; ++t) {
            int m = (wave * 4 + t) * 16 + quad * 4;
            float* op = out + ((size_t)(b * 256 + m)) * 4096 + pimg;
            #pragma unroll
            for (int r = 0; r < 4; ++r)
                op[(size_t)r * 4096] = acc[t][nt][r] + bias[m + r];
        }
    }
}

// ---------------------------------------------------------------------------
extern "C" void kernel_launch(void* const* d_in, const int* in_sizes, int n_in,
                              void* d_out, int out_size, void* d_ws, size_t ws_size,
                              hipStream_t stream) {
    const float* x    = (const float*)d_in[0];   // [4,256,64,64]
    const float* off  = (const float*)d_in[1];   // [4,18,64,64]
    const float* w    = (const float*)d_in[2];   // [256,256,3,3]
    const float* bias = (const float*)d_in[3];   // [256]
    float* out = (float*)d_out;                  // [4,256,64,64]

    bf16* wq = (bf16*)d_ws;                               // 1,179,648 B
    bf16* xt = (bf16*)((char*)d_ws + (size_t)589824 * 2); // 8,388,608 B

    pack_weight_k<<<2304, 256, 0, stream>>>(w, wq);
    transpose_x_k<<<1024, 256, 0, stream>>>(x, xt);
    deform_gemm_k<<<512, 256, 0, stream>>>(xt, off, wq, bias, out);
}

// Round 3
// 125.459 us; speedup vs baseline: 2.1872x; 1.5958x over previous
//
#include <hip/hip_runtime.h>

typedef __bf16 bf16;
typedef __bf16 bf16x4 __attribute__((ext_vector_type(4)));
typedef __bf16 bf16x8 __attribute__((ext_vector_type(8)));
typedef float  f32x4  __attribute__((ext_vector_type(4)));

#define CIN   256
#define COUT  256
#define KK    9
#define KDIM  (CIN * KK)     // 2304
#define KITERS 72            // KDIM / 32
#define PXW   32             // pixels per WG
#define SROW  264            // 256 + 8 bf16 pad

// ---------------------------------------------------------------------------
// Kernel 1: weight [O][C][3][3] fp32 -> MFMA-fragment-ordered bf16:
//   wq[ ((m*72 + kt)*64 + lane)*8 + j ] = W[o=m*16+l16][k=kt*32+quad*8+j]
//   k -> (tap = k>>8, c = k&255);  lane = quad*16+l16.
// ---------------------------------------------------------------------------
__global__ void pack_weight_k(const float* __restrict__ w, bf16* __restrict__ wq) {
    int idx  = blockIdx.x * 256 + threadIdx.x;   // < 589824
    int j    = idx & 7;
    int lane = (idx >> 3) & 63;
    int rest = idx >> 9;            // m*72 + kt
    int kt   = rest % KITERS;
    int m    = rest / KITERS;
    int l16  = lane & 15;
    int quad = lane >> 4;
    int o    = m * 16 + l16;
    int k    = kt * 32 + quad * 8 + j;
    int tap  = k >> 8;
    int c    = k & 255;
    wq[idx] = (bf16)w[(size_t)o * KDIM + c * KK + tap];
}

// ---------------------------------------------------------------------------
// Kernel 2: x [B][C][64][64] fp32 -> channels-last bf16 xt [B][64][64][C]
// ---------------------------------------------------------------------------
__global__ void transpose_x_k(const float* __restrict__ x, bf16* __restrict__ xt) {
    __shared__ bf16 tile[64][72];
    int wg = blockIdx.x;          // 1024 = 4 b * 4 ctile * 64 ptile
    int pt = wg & 63;
    int ct = (wg >> 6) & 3;
    int b  = wg >> 8;
    int lane = threadIdx.x & 63;
    int row  = threadIdx.x >> 6;  // 0..3
    const float* src = x + ((size_t)(b * 256 + ct * 64)) * 4096 + pt * 64;
    for (int c = row; c < 64; c += 4)
        tile[c][lane] = (bf16)src[(size_t)c * 4096 + lane];
    __syncthreads();
    bf16* dst = xt + ((size_t)(b * 4096 + pt * 64)) * 256 + ct * 64;
    for (int p = row; p < 64; p += 4)
        dst[(size_t)p * 256 + lane] = tile[lane][p];
}

// ---------------------------------------------------------------------------
// Kernel 3: fused sampling -> LDS -> MFMA GEMM
// WG = 512 thr (8 waves), 32 pixels.  Wave = M32 (2 mtiles) x N32 (2 ntiles).
// 512 WGs -> 2 WGs/CU -> 16 waves/CU (50% occupancy).
// Branch-free clamped gathers: all 16 per wave issue in one basic block.
// ---------------------------------------------------------------------------
__global__ __launch_bounds__(512, 4) void deform_gemm_k(
    const bf16*  __restrict__ xt,
    const float* __restrict__ off,
    const bf16*  __restrict__ wq,
    const float* __restrict__ bias,
    float*       __restrict__ out) {

    __shared__ bf16 S[PXW][SROW];   // 16,896 B

    int tid  = threadIdx.x;
    int wave = tid >> 6;            // 0..7
    int lane = tid & 63;
    int quad = lane >> 4;
    int l16  = lane & 15;
    int pix0 = blockIdx.x * PXW;
    int c    = lane * 4;            // this lane's 4 channels

    // tap-invariant per-pixel setup (4 pixels per wave)
    int ybase[4], xbase[4];
    unsigned base[4];               // 32-bit element offset into xt
    const float* obp[4];
    #pragma unroll
    for (int i = 0; i < 4; ++i) {
        int n    = wave * 4 + i;
        int pg   = pix0 + n;
        int b    = pg >> 12;
        int pimg = pg & 4095;
        ybase[i] = pimg >> 6;
        xbase[i] = pimg & 63;
        obp[i]   = off + (size_t)b * 18 * 4096 + pimg;
        base[i]  = (unsigned)b * 1048576u + (unsigned)c;
    }

    f32x4 acc[2][2];
    #pragma unroll
    for (int mt = 0; mt < 2; ++mt)
        #pragma unroll
        for (int nt = 0; nt < 2; ++nt)
            acc[mt][nt] = (f32x4){0.f, 0.f, 0.f, 0.f};

    for (int tap = 0; tap < KK; ++tap) {
        int ty = tap / 3 - 1;
        int tx = tap % 3 - 1;

        // ---- compute addresses + weights for all 4 pixels (branch-free) ----
        unsigned o32[4][4];
        float    w4[4][4];
        #pragma unroll
        for (int i = 0; i < 4; ++i) {
            float oy = obp[i][(size_t)(2 * tap) * 4096];
            float ox = obp[i][(size_t)(2 * tap + 1) * 4096];
            float py = (float)(ybase[i] + ty) + oy;
            float px = (float)(xbase[i] + tx) + ox;
            float fy = floorf(py), fx = floorf(px);
            int   y0 = (int)fy,    x0 = (int)fx;
            float wy1 = py - fy, wx1 = px - fx;
            float wy0 = 1.f - wy1, wx0 = 1.f - wx1;
            wy0 = ((unsigned)y0       < 64u) ? wy0 : 0.f;
            wy1 = ((unsigned)(y0 + 1) < 64u) ? wy1 : 0.f;
            wx0 = ((unsigned)x0       < 64u) ? wx0 : 0.f;
            wx1 = ((unsigned)(x0 + 1) < 64u) ? wx1 : 0.f;
            int yc0 = min(max(y0, 0), 63),     yc1 = min(max(y0 + 1, 0), 63);
            int xc0 = min(max(x0, 0), 63),     xc1 = min(max(x0 + 1, 0), 63);
            o32[i][0] = base[i] + (unsigned)((yc0 * 64 + xc0) * 256);
            o32[i][1] = base[i] + (unsigned)((yc0 * 64 + xc1) * 256);
            o32[i][2] = base[i] + (unsigned)((yc1 * 64 + xc0) * 256);
            o32[i][3] = base[i] + (unsigned)((yc1 * 64 + xc1) * 256);
            w4[i][0] = wy0 * wx0; w4[i][1] = wy0 * wx1;
            w4[i][2] = wy1 * wx0; w4[i][3] = wy1 * wx1;
        }

        // ---- issue all 16 gathers back-to-back ----
        bf16x4 v[4][4];
        #pragma unroll
        for (int i = 0; i < 4; ++i)
            #pragma unroll
            for (int j = 0; j < 4; ++j)
                v[i][j] = *reinterpret_cast<const bf16x4*>(xt + o32[i][j]);

        // ---- blend + LDS write ----
        #pragma unroll
        for (int i = 0; i < 4; ++i) {
            float a0 = 0.f, a1 = 0.f, a2 = 0.f, a3 = 0.f;
            #pragma unroll
            for (int j = 0; j < 4; ++j) {
                float wt = w4[i][j];
                a0 += wt * (float)v[i][j][0];
                a1 += wt * (float)v[i][j][1];
                a2 += wt * (float)v[i][j][2];
                a3 += wt * (float)v[i][j][3];
            }
            bf16x4 sv;
            sv[0] = (bf16)a0; sv[1] = (bf16)a1;
            sv[2] = (bf16)a2; sv[3] = (bf16)a3;
            *reinterpret_cast<bf16x4*>(&S[wave * 4 + i][c]) = sv;
        }
        __syncthreads();

        // ---- GEMM over this tap's k=256 ----
        const bf16* sp0 = &S[l16][quad * 8];
        const bf16* sp1 = &S[16 + l16][quad * 8];
        const bf16* ap0 = wq + ((size_t)((2 * wave) * KITERS + tap * 8) * 64 + lane) * 8;
        const bf16* ap1 = ap0 + (size_t)KITERS * 64 * 8;
        #pragma unroll
        for (int kki = 0; kki < 8; ++kki) {
            bf16x8 b0 = *reinterpret_cast<const bf16x8*>(sp0 + kki * 32);
            bf16x8 b1 = *reinterpret_cast<const bf16x8*>(sp1 + kki * 32);
            bf16x8 a0 = *reinterpret_cast<const bf16x8*>(ap0 + (size_t)kki * 512);
            bf16x8 a1 = *reinterpret_cast<const bf16x8*>(ap1 + (size_t)kki * 512);
            acc[0][0] = __builtin_amdgcn_mfma_f32_16x16x32_bf16(a0, b0, acc[0][0], 0, 0, 0);
            acc[0][1] = __builtin_amdgcn_mfma_f32_16x16x32_bf16(a0, b1, acc[0][1], 0, 0, 0);
            acc[1][0] = __builtin_amdgcn_mfma_f32_16x16x32_bf16(a1, b0, acc[1][0], 0, 0, 0);
            acc[1][1] = __builtin_amdgcn_mfma_f32_16x16x32_bf16(a1, b1, acc[1][1], 0, 0, 0);
        }
        __syncthreads();   // S reused next tap
    }

    // ---- epilogue: C/D layout col=l16, row=quad*4+r ----
    #pragma unroll
    for (int nt = 0; nt < 2; ++nt) {
        int pg   = pix0 + nt * 16 + l16;
        int b    = pg >> 12;
        int pimg = pg & 4095;
        #pragma unroll
        for (int mt = 0; mt < 2; ++mt) {
            int m = (2 * wave + mt) * 16 + quad * 4;
            float* op = out + ((size_t)(b * 256 + m)) * 4096 + pimg;
            #pragma unroll
            for (int r = 0; r < 4; ++r)
                op[(size_t)r * 4096] = acc[mt][nt][r] + bias[m + r];
        }
    }
}

// ---------------------------------------------------------------------------
extern "C" void kernel_launch(void* const* d_in, const int* in_sizes, int n_in,
                              void* d_out, int out_size, void* d_ws, size_t ws_size,
                              hipStream_t stream) {
    const float* x    = (const float*)d_in[0];   // [4,256,64,64]
    const float* off  = (const float*)d_in[1];   // [4,18,64,64]
    const float* w    = (const float*)d_in[2];   // [256,256,3,3]
    const float* bias = (const float*)d_in[3];   // [256]
    float* out = (float*)d_out;                  // [4,256,64,64]

    bf16* wq = (bf16*)d_ws;                               // 1,179,648 B
    bf16* xt = (bf16*)((char*)d_ws + (size_t)589824 * 2); // 8,388,608 B

    pack_weight_k<<<2304, 256, 0, stream>>>(w, wq);
    transpose_x_k<<<1024, 256, 0, stream>>>(x, xt);
    deform_gemm_k<<<512, 512, 0, stream>>>(xt, off, wq, bias, out);
}

// Round 4
// 123.599 us; speedup vs baseline: 2.2202x; 1.0151x over previous
//
#include <hip/hip_runtime.h>

typedef __bf16 bf16;
typedef __bf16 bf16x4 __attribute__((ext_vector_type(4)));
typedef __bf16 bf16x8 __attribute__((ext_vector_type(8)));
typedef float  f32x4  __attribute__((ext_vector_type(4)));

#define CIN   256
#define KK    9
#define KDIM  2304
#define KITERS 72            // KDIM / 32
#define PXW   32             // pixels per WG
#define SROW  264            // 256 + 8 bf16 pad

// broadcast a wave-uniform float into an SGPR (frees VGPRs across GEMM)
__device__ __forceinline__ float sread(float f) {
    return __builtin_bit_cast(float,
        __builtin_amdgcn_readfirstlane(__builtin_bit_cast(int, f)));
}

// ---------------------------------------------------------------------------
// Fused prep: blocks [0,1024) transpose x -> channels-last bf16 xt;
//             blocks [1024,3328) pack weight -> MFMA-fragment-ordered wq:
//   wq[ ((m*72 + kt)*64 + lane)*8 + j ] = W[o=m*16+l16][k=kt*32+quad*8+j]
//   k -> (tap = k>>8, c = k&255);  lane = quad*16+l16.
// ---------------------------------------------------------------------------
__global__ __launch_bounds__(256) void prep_k(const float* __restrict__ x,
                                              const float* __restrict__ w,
                                              bf16* __restrict__ xt,
                                              bf16* __restrict__ wq) {
    int bid = blockIdx.x;
    int tid = threadIdx.x;
    if (bid < 1024) {
        __shared__ bf16 tile[64][72];        // px-major; rows 144 B (16B-aligned)
        int pt = bid & 63, ct = (bid >> 6) & 3, b = bid >> 8;
        int lane = tid & 63, row = tid >> 6;
        const float* src = x + ((size_t)(b * 256 + ct * 64)) * 4096 + pt * 64;
        #pragma unroll
        for (int cc = row; cc < 64; cc += 4)
            tile[lane][cc] = (bf16)src[(size_t)cc * 4096 + lane];
        __syncthreads();
        bf16* dst = xt + ((size_t)(b * 4096 + pt * 64)) * 256 + ct * 64;
        int p = tid >> 3, j = tid & 7;       // 32 px-rows x 8 chunks, 2 passes
        #pragma unroll
        for (int pp = p; pp < 64; pp += 32)
            *reinterpret_cast<bf16x8*>(dst + (size_t)pp * 256 + j * 8) =
                *reinterpret_cast<const bf16x8*>(&tile[pp][j * 8]);
    } else {
        int idx  = (bid - 1024) * 256 + tid;   // < 589824
        int j    = idx & 7;
        int lane = (idx >> 3) & 63;
        int rest = idx >> 9;                   // m*72 + kt
        int kt   = rest % KITERS;
        int m    = rest / KITERS;
        int l16  = lane & 15;
        int quad = lane >> 4;
        int o    = m * 16 + l16;
        int k    = kt * 32 + quad * 8 + j;
        int tap  = k >> 8;
        int cc   = k & 255;
        wq[idx] = (bf16)w[(size_t)o * KDIM + cc * KK + tap];
    }
}

// ---------------------------------------------------------------------------
// Fused sampling -> LDS (double-buffered) -> MFMA GEMM
// WG = 512 thr (8 waves), 32 pixels. Wave = M32 x N32. Grid 512 = 2 WGs/CU.
// One barrier per tap; tap t+1 gathers issue before GEMM(t) MFMAs.
// ---------------------------------------------------------------------------
__global__ __launch_bounds__(512, 4) void deform_gemm_k(
    const bf16*  __restrict__ xt,
    const float* __restrict__ off,
    const bf16*  __restrict__ wq,
    const float* __restrict__ bias,
    float*       __restrict__ out) {

    __shared__ bf16 S[2][PXW][SROW];   // 33,792 B

    int tid  = threadIdx.x;
    int wave = tid >> 6;               // 0..7
    int lane = tid & 63;
    int quad = lane >> 4;
    int l16  = lane & 15;
    int pix0 = blockIdx.x * PXW;
    int c    = lane * 4;               // this lane's 4 channels

    // tap-invariant per-pixel setup (4 pixels per wave)
    int ybase[4], xbase[4];
    unsigned base[4], ooff[4];
    #pragma unroll
    for (int i = 0; i < 4; ++i) {
        int n    = wave * 4 + i;
        int pg   = pix0 + n;
        int b    = pg >> 12;
        int pimg = pg & 4095;
        ybase[i] = pimg >> 6;
        xbase[i] = pimg & 63;
        ooff[i]  = (unsigned)b * 73728u + (unsigned)pimg;  // into off[]
        base[i]  = (unsigned)b * 1048576u + (unsigned)c;   // into xt[]
    }

    f32x4 acc[2][2];
    #pragma unroll
    for (int mt = 0; mt < 2; ++mt)
        #pragma unroll
        for (int nt = 0; nt < 2; ++nt)
            acc[mt][nt] = (f32x4){0.f, 0.f, 0.f, 0.f};

    bf16x4 v[4][4];      // prefetched corner data (per-lane, VGPR)
    float  w4[4][4];     // bilinear weights (wave-uniform -> SGPR via sread)

    auto gather = [&](int tap) {
        int ty = tap / 3 - 1;
        int tx = tap % 3 - 1;
        #pragma unroll
        for (int i = 0; i < 4; ++i) {
            float oy = off[(size_t)ooff[i] + (size_t)(2 * tap) * 4096];
            float ox = off[(size_t)ooff[i] + (size_t)(2 * tap + 1) * 4096];
            float py = (float)(ybase[i] + ty) + oy;
            float px = (float)(xbase[i] + tx) + ox;
            float fy = floorf(py), fx = floorf(px);
            int   y0 = (int)fy,    x0 = (int)fx;
            float wy1 = py - fy, wx1 = px - fx;
            float wy0 = 1.f - wy1, wx0 = 1.f - wx1;
            wy0 = ((unsigned)y0       < 64u) ? wy0 : 0.f;
            wy1 = ((unsigned)(y0 + 1) < 64u) ? wy1 : 0.f;
            wx0 = ((unsigned)x0       < 64u) ? wx0 : 0.f;
            wx1 = ((unsigned)(x0 + 1) < 64u) ? wx1 : 0.f;
            int yc0 = min(max(y0, 0), 63),     yc1 = min(max(y0 + 1, 0), 63);
            int xc0 = min(max(x0, 0), 63),     xc1 = min(max(x0 + 1, 0), 63);
            unsigned u0 = (unsigned)((yc0 * 64 + xc0) * 256);
            unsigned u1 = (unsigned)((yc0 * 64 + xc1) * 256);
            unsigned u2 = (unsigned)((yc1 * 64 + xc0) * 256);
            unsigned u3 = (unsigned)((yc1 * 64 + xc1) * 256);
            w4[i][0] = sread(wy0 * wx0); w4[i][1] = sread(wy0 * wx1);
            w4[i][2] = sread(wy1 * wx0); w4[i][3] = sread(wy1 * wx1);
            v[i][0] = *reinterpret_cast<const bf16x4*>(xt + base[i] + u0);
            v[i][1] = *reinterpret_cast<const bf16x4*>(xt + base[i] + u1);
            v[i][2] = *reinterpret_cast<const bf16x4*>(xt + base[i] + u2);
            v[i][3] = *reinterpret_cast<const bf16x4*>(xt + base[i] + u3);
        }
    };

    auto blend = [&](int buf) {
        #pragma unroll
        for (int i = 0; i < 4; ++i) {
            float a0 = 0.f, a1 = 0.f, a2 = 0.f, a3 = 0.f;
            #pragma unroll
            for (int j = 0; j < 4; ++j) {
                float wt = w4[i][j];
                a0 += wt * (float)v[i][j][0];
                a1 += wt * (float)v[i][j][1];
                a2 += wt * (float)v[i][j][2];
                a3 += wt * (float)v[i][j][3];
            }
            bf16x4 sv;
            sv[0] = (bf16)a0; sv[1] = (bf16)a1;
            sv[2] = (bf16)a2; sv[3] = (bf16)a3;
            *reinterpret_cast<bf16x4*>(&S[buf][wave * 4 + i][c]) = sv;
        }
    };

    auto gemm = [&](int buf, int tap) {
        const bf16* sp0 = &S[buf][l16][quad * 8];
        const bf16* sp1 = &S[buf][16 + l16][quad * 8];
        const bf16* ap0 = wq + ((size_t)((2 * wave) * KITERS + tap * 8) * 64 + lane) * 8;
        const bf16* ap1 = ap0 + (size_t)KITERS * 64 * 8;
        #pragma unroll
        for (int kki = 0; kki < 8; ++kki) {
            bf16x8 b0 = *reinterpret_cast<const bf16x8*>(sp0 + kki * 32);
            bf16x8 b1 = *reinterpret_cast<const bf16x8*>(sp1 + kki * 32);
            bf16x8 a0 = *reinterpret_cast<const bf16x8*>(ap0 + (size_t)kki * 512);
            bf16x8 a1 = *reinterpret_cast<const bf16x8*>(ap1 + (size_t)kki * 512);
            acc[0][0] = __builtin_amdgcn_mfma_f32_16x16x32_bf16(a0, b0, acc[0][0], 0, 0, 0);
            acc[0][1] = __builtin_amdgcn_mfma_f32_16x16x32_bf16(a0, b1, acc[0][1], 0, 0, 0);
            acc[1][0] = __builtin_amdgcn_mfma_f32_16x16x32_bf16(a1, b0, acc[1][0], 0, 0, 0);
            acc[1][1] = __builtin_amdgcn_mfma_f32_16x16x32_bf16(a1, b1, acc[1][1], 0, 0, 0);
        }
    };

    // prologue: tap 0 into buffer 0
    gather(0);
    blend(0);
    __syncthreads();

    for (int tap = 0; tap < KK; ++tap) {
        int cur = tap & 1;
        if (tap + 1 < KK) gather(tap + 1);   // loads in flight under the MFMAs
        gemm(cur, tap);
        if (tap + 1 < KK) blend(cur ^ 1);
        __syncthreads();
    }

    // epilogue: C/D layout col=l16, row=quad*4+r
    #pragma unroll
    for (int nt = 0; nt < 2; ++nt) {
        int pg   = pix0 + nt * 16 + l16;
        int b    = pg >> 12;
        int pimg = pg & 4095;
        #pragma unroll
        for (int mt = 0; mt < 2; ++mt) {
            int m = (2 * wave + mt) * 16 + quad * 4;
            float* op = out + ((size_t)(b * 256 + m)) * 4096 + pimg;
            #pragma unroll
            for (int r = 0; r < 4; ++r)
                op[(size_t)r * 4096] = acc[mt][nt][r] + bias[m + r];
        }
    }
}

// ---------------------------------------------------------------------------
extern "C" void kernel_launch(void* const* d_in, const int* in_sizes, int n_in,
                              void* d_out, int out_size, void* d_ws, size_t ws_size,
                              hipStream_t stream) {
    const float* x    = (const float*)d_in[0];   // [4,256,64,64]
    const float* off  = (const float*)d_in[1];   // [4,18,64,64]
    const float* w    = (const float*)d_in[2];   // [256,256,3,3]
    const float* bias = (const float*)d_in[3];   // [256]
    float* out = (float*)d_out;                  // [4,256,64,64]

    bf16* wq = (bf16*)d_ws;                               // 1,179,648 B
    bf16* xt = (bf16*)((char*)d_ws + (size_t)589824 * 2); // 8,388,608 B

    prep_k<<<3328, 256, 0, stream>>>(x, w, xt, wq);
    deform_gemm_k<<<512, 512, 0, stream>>>(xt, off, wq, bias, out);
}